// Round 8
// baseline (209.498 us; speedup 1.0000x reference)
//
#include <hip/hip_runtime.h>
#include <hip/hip_bf16.h>

typedef unsigned short u16;
typedef unsigned int u32;
typedef __attribute__((ext_vector_type(8))) short short8;
typedef __attribute__((ext_vector_type(4))) float floatx4;

#define NB 32
#define NCI 256
#define NCO 256
#define NW 4096
#define NK 5

#define W2_BYTES (40 * 256 * 64)       // [cb,t][co] 64-B rows, 655360 B

#define XROWB 64                       // 32 ci' bf16 per row
#define XROWS 136                      // r = w - w0 + 4; rows 2..133 used
#define XBUF (XROWS * XROWB)           // 8704 B
#define XSWZ(r) ((((r) >> 1) & 3) << 4)   // validated conflict-free (r6/r7)

// ---------------- pre-kernel: W fp32 -> bf16, [cb,t][co][32ci] 64-B rows ----------------

__global__ void wprep(const float* __restrict__ wgt, u16* __restrict__ W2) {
    int i = blockIdx.x * 256 + threadIdx.x;       // co*1280 + ci*5 + k
    if (i >= NCO * NCI * NK) return;
    int k  = i % NK;
    int ci = (i / NK) % NCI;
    int co = i / (NCI * NK);
    int cb = ci >> 5, cr = ci & 31;
    __hip_bfloat16 h = __float2bfloat16(wgt[i]);
    W2[((size_t)(cb * NK + k) * 256 + co) * 32 + cr] = *reinterpret_cast<u16*>(&h);
}

__device__ __forceinline__ u16 bf16bits(float f) {
    __hip_bfloat16 h = __float2bfloat16(f);
    return *reinterpret_cast<u16*>(&h);
}

// ---------------- fused conv ----------------
// grid 1024 = 32 w-tiles x 32 batch; block 512 thr = 8 waves.
// block tile 256co x 128w; wave tile 64co x 64w (wm=wave>>1, wn=wave&1);
// acc[4][4] = 64 regs -> combined regs ~120 -> 4 waves/SIMD (the point).
// af from global W2 (L1/L2-hot, 1 KB contiguous per wave-load);
// bf from LDS X (fused fp32->bf16, swizzled, dbuf, 1 barrier/cb).

__global__ __launch_bounds__(512, 4)
void conv_mfma(const float* __restrict__ x, const u16* __restrict__ W2,
               const float* __restrict__ bias, float* __restrict__ out) {
    __shared__ __align__(16) char xlds[2 * XBUF];   // 17408 B

    const int bid  = blockIdx.x;
    const int wt   = bid & 31;
    const int b    = bid >> 5;
    const int tid  = threadIdx.x;
    const int lane = tid & 63;
    const int wave = tid >> 6;
    const int wm   = wave >> 1;        // co strip: wm*64
    const int wn   = wave & 1;         // w strip:  wn*64
    const int mrow = lane & 15;
    const int g    = lane >> 4;        // 0..3
    const int w0   = wt * 128;

    floatx4 acc[4][4];
#pragma unroll
    for (int mi = 0; mi < 4; ++mi)
#pragma unroll
        for (int ni = 0; ni < 4; ++ni)
            acc[mi][ni] = (floatx4){0.f, 0.f, 0.f, 0.f};

    const float* xb = x + (size_t)b * NCI * NW;

    // x staging: thread covers one 16-B chunk (8 ci) of one main row
    const int wloc = tid & 127;        // row r = 4 + wloc  (w = w0 + wloc)
    const int q    = tid >> 7;         // ci chunk 0..3
    const int soff = (4 + wloc) * XROWB + ((q * 16) ^ XSWZ(4 + wloc));
    const float* xcol = xb + (size_t)(q * 8) * NW + w0 + wloc;   // + cb*32*NW + j*NW

    // halo: threads 0..15 -> rows {2,3,132,133} (w0-2,w0-1,w0+128,w0+129)
    const int hidx = tid >> 2;         // 0..3 (only tid<16)
    const int hq   = tid & 3;
    const int hr   = (hidx < 2) ? (2 + hidx) : (130 + hidx);
    const int hw   = w0 + ((hidx < 2) ? (hidx - 2) : (126 + hidx));
    const bool hok = (tid < 16) && (hw >= 0) && (hw < NW);
    const int hoff = hr * XROWB + ((hq * 16) ^ XSWZ(hr));

    // ---------- prologue: stage cb = 0 into buf 0 ----------
    {
        u32 p[4];
#pragma unroll
        for (int jp = 0; jp < 4; ++jp) {
            float a0 = xcol[(size_t)(2 * jp) * NW];
            float a1 = xcol[(size_t)(2 * jp + 1) * NW];
            p[jp] = (u32)bf16bits(a0) | ((u32)bf16bits(a1) << 16);
        }
        *(int4*)(xlds + soff) = *(int4*)p;
        if (tid < 16) {
            u32 hp[4];
#pragma unroll
            for (int jp = 0; jp < 4; ++jp) {
                float a0 = hok ? xb[(size_t)(hq * 8 + 2 * jp) * NW + hw] : 0.f;
                float a1 = hok ? xb[(size_t)(hq * 8 + 2 * jp + 1) * NW + hw] : 0.f;
                hp[jp] = (u32)bf16bits(a0) | ((u32)bf16bits(a1) << 16);
            }
            *(int4*)(xlds + hoff) = *(int4*)hp;
        }
    }
    __syncthreads();

    // ---------- main loop over 8 ci-blocks ----------
    for (int cb = 0; cb < 8; ++cb) {
        const char* cur = xlds + (cb & 1) * XBUF;
        char* nxt       = xlds + ((cb + 1) & 1) * XBUF;
        const bool more = (cb < 7);

        // issue-early: x global loads for cb+1 (pack immediately, 4 u32 live)
        u32 p[4], hp[4];
        if (more) {
            const float* s = xcol + (size_t)((cb + 1) * 32) * NW;
#pragma unroll
            for (int jp = 0; jp < 4; ++jp) {
                float a0 = s[(size_t)(2 * jp) * NW];
                float a1 = s[(size_t)(2 * jp + 1) * NW];
                p[jp] = (u32)bf16bits(a0) | ((u32)bf16bits(a1) << 16);
            }
            if (tid < 16) {
                const float* sh = xb + (size_t)((cb + 1) * 32 + hq * 8) * NW + hw;
#pragma unroll
                for (int jp = 0; jp < 4; ++jp) {
                    float a0 = hok ? sh[(size_t)(2 * jp) * NW] : 0.f;
                    float a1 = hok ? sh[(size_t)(2 * jp + 1) * NW] : 0.f;
                    hp[jp] = (u32)bf16bits(a0) | ((u32)bf16bits(a1) << 16);
                }
            }
        }

        // compute: 5 taps x (4 af-global + 4 bf-LDS + 16 MFMA)
#pragma unroll
        for (int t = 0; t < NK; ++t) {
            const char* wtile = (const char*)W2 +
                ((size_t)(cb * NK + t) * 256 + wm * 64) * 64;
            short8 af[4], bf[4];
#pragma unroll
            for (int mi = 0; mi < 4; ++mi)
                af[mi] = *(const short8*)(wtile + (mi * 16 + mrow) * 64 + g * 16);
#pragma unroll
            for (int ni = 0; ni < 4; ++ni) {
                int r = wn * 64 + ni * 16 + mrow + t + 2;
                bf[ni] = *(const short8*)(cur + r * XROWB + ((g * 16) ^ XSWZ(r)));
            }
#pragma unroll
            for (int mi = 0; mi < 4; ++mi)
#pragma unroll
                for (int ni = 0; ni < 4; ++ni)
                    acc[mi][ni] = __builtin_amdgcn_mfma_f32_16x16x32_bf16(
                        af[mi], bf[ni], acc[mi][ni], 0, 0, 0);
        }

        // write-late + single barrier
        if (more) {
            *(int4*)(nxt + soff) = *(int4*)p;
            if (tid < 16) *(int4*)(nxt + hoff) = *(int4*)hp;
            __syncthreads();
        }
    }

    // ---------- epilogue: C/D col=lane&15 (w), row=g*4+r (co) ----------
#pragma unroll
    for (int mi = 0; mi < 4; ++mi) {
        int cobase = wm * 64 + mi * 16 + g * 4;
        float bv[4];
#pragma unroll
        for (int r = 0; r < 4; ++r) bv[r] = bias[cobase + r];
#pragma unroll
        for (int ni = 0; ni < 4; ++ni) {
            int col = w0 + wn * 64 + ni * 16 + mrow;
#pragma unroll
            for (int r = 0; r < 4; ++r)
                out[((size_t)b * NCO + cobase + r) * NW + col] =
                    acc[mi][ni][r] + bv[r];
        }
    }
}

// ---------------- fallback (ws too small): naive fp32 ----------------

__global__ void conv_naive(const float* __restrict__ x, const float* __restrict__ wgt,
                           const float* __restrict__ bias, float* __restrict__ out) {
    int w  = blockIdx.x * 256 + threadIdx.x;
    int co = blockIdx.y;
    int b  = blockIdx.z;
    float acc = bias[co];
    for (int ci = 0; ci < NCI; ci++) {
        const float* xr = x + ((size_t)b * NCI + ci) * NW;
        const float* wr = wgt + ((size_t)co * NCI + ci) * NK;
#pragma unroll
        for (int k = 0; k < NK; k++) {
            int wi = w + k - 2;
            if (wi >= 0 && wi < NW) acc += xr[wi] * wr[k];
        }
    }
    out[((size_t)b * NCO + co) * NW + w] = acc;
}

// ---------------- launch ----------------

extern "C" void kernel_launch(void* const* d_in, const int* in_sizes, int n_in,
                              void* d_out, int out_size, void* d_ws, size_t ws_size,
                              hipStream_t stream) {
    const float* x    = (const float*)d_in[0];
    const float* wgt  = (const float*)d_in[1];
    const float* bias = (const float*)d_in[2];
    float* out        = (float*)d_out;

    if (ws_size < (size_t)W2_BYTES) {
        conv_naive<<<dim3(NW / 256, NCO, NB), 256, 0, stream>>>(x, wgt, bias, out);
        return;
    }

    u16* W2 = (u16*)d_ws;
    wprep<<<(NCO * NCI * NK + 255) / 256, 256, 0, stream>>>(wgt, W2);
    conv_mfma<<<1024, 512, 0, stream>>>(x, W2, bias, out);
}

// Round 9
// 95.603 us; speedup vs baseline: 2.1913x; 2.1913x over previous
//
#include <hip/hip_runtime.h>
#include <hip/hip_bf16.h>

typedef unsigned short u16;
typedef unsigned int u32;
typedef __attribute__((ext_vector_type(8))) short short8;
typedef __attribute__((ext_vector_type(4))) float floatx4;

#define NB 32
#define NCI 256
#define NCO 256
#define NW 4096
#define NK 5

#define WSTEP 16384                     // per (cb,t) W tile: 256 co x 64 B, pre-swizzled
#define W2_BYTES (40 * WSTEP)           // 655360

#define XROWB 64                        // 32 ci' bf16
#define XROWS 260                       // rloc = (w - w0) + 2, 0..259
#define XBUF (XROWS * XROWB)            // 16640 B
#define XSWZ(r) ((((r) >> 1) & 3) << 4) // validated conflict-free r6-r8

#define FENCE asm volatile("" ::: "memory")
#define VM0   asm volatile("s_waitcnt vmcnt(0)" ::: "memory")
#define LK0   asm volatile("s_waitcnt lgkmcnt(0)" ::: "memory")

// ---------------- pre-kernel: W fp32 -> bf16, pre-swizzled DMA image ----------------

__global__ void wprep(const float* __restrict__ wgt, u16* __restrict__ W2) {
    int i = blockIdx.x * 256 + threadIdx.x;        // co*1280 + ci*5 + k
    if (i >= NCO * NCI * NK) return;
    int k  = i % NK;
    int ci = (i / NK) % NCI;
    int co = i / (NCI * NK);
    int cb = ci >> 5, cr = ci & 31;
    int s    = cb * NK + k;
    int slot = (cr >> 3) ^ ((co >> 1) & 3);        // phys 16-B slot (T21 pre-swizzle)
    __hip_bfloat16 h = __float2bfloat16(wgt[i]);
    W2[(size_t)(s * 256 + co) * 32 + slot * 8 + (cr & 7)] = *reinterpret_cast<u16*>(&h);
}

__device__ __forceinline__ u16 bf16bits(float f) {
    __hip_bfloat16 h = __float2bfloat16(f);
    return *reinterpret_cast<u16*>(&h);
}

__device__ __forceinline__ void gload_lds16(const void* gsrc, void* ldst) {
    __builtin_amdgcn_global_load_lds(
        (const __attribute__((address_space(1))) unsigned int*)gsrc,
        (__attribute__((address_space(3))) unsigned int*)ldst, 16, 0, 0);
}

// ---------------- fused conv, 5-step/cb pipelined schedule ----------------
// grid 512 = 16 w-tiles x 32 b; block 512 thr = 8 waves; wave tile 128co x 64w.
// Per step (cb,t): issue W-DMA(s+1, 16KB) + x slice (4 HBM loads) ->
// 12 ds_reads + 32 MFMA hide them -> vmcnt(0) + raw s_barrier (no cross-
// barrier in-flight: race-safe). W dbuf 2x16KB, X dbuf 2x16.6KB = 66 KB LDS.

__global__ __launch_bounds__(512, 2)
void conv_mfma(const float* __restrict__ x, const u16* __restrict__ W2,
               const float* __restrict__ bias, float* __restrict__ out) {
    __shared__ __align__(16) char smem[2 * WSTEP + 2 * XBUF];
    char* const wlds = smem;                 // 2 x 16384
    char* const xlds = smem + 2 * WSTEP;     // 2 x 16640

    const int bid  = blockIdx.x;
    const int wt   = bid & 15;
    const int b    = bid >> 4;
    const int tid  = threadIdx.x;
    const int lane = tid & 63;
    const int wave = tid >> 6;
    const int wm   = wave >> 2;        // co strip: wm*128
    const int wn   = wave & 3;         // w strip:  wn*64
    const int mrow = lane & 15;
    const int g    = lane >> 4;        // 0..3
    const int w0   = wt * 256;

    floatx4 acc[8][4];
#pragma unroll
    for (int mi = 0; mi < 8; ++mi)
#pragma unroll
        for (int ni = 0; ni < 4; ++ni)
            acc[mi][ni] = (floatx4){0.f, 0.f, 0.f, 0.f};

    const float* xb   = x + (size_t)b * NCI * NW;
    const char*  wimg = (const char*)W2;

    // x staging: thread -> one w (wloc), 16 ci (half h); row rloc = 2 + wloc
    const int wloc = tid & 255;
    const int h    = tid >> 8;
    const int soff0 = (2 + wloc) * XROWB + ((h * 32) ^ XSWZ(2 + wloc));
    const int soff1 = (2 + wloc) * XROWB + ((h * 32 + 16) ^ XSWZ(2 + wloc));
    const float* xcol = xb + w0 + wloc;          // + ci*NW

    // halo: 1 uniform clamped load per wave; lanes 0..15 meaningful
    const int hidx = wave * 16 + (lane & 15);    // 0..127 -> (ri, ci)
    const int hri  = hidx >> 5;                  // 0..3
    const int hci  = hidx & 31;
    const int hwg  = (hri < 2) ? (w0 - 2 + hri) : (w0 + 256 + (hri - 2));
    const int hwc  = (hwg < 0) ? 0 : ((hwg > NW - 1) ? (NW - 1) : hwg);
    const bool hok = (hwg >= 0) && (hwg < NW);
    const int hrloc = (hri < 2) ? hri : (258 + (hri - 2));
    const int hoff  = hrloc * XROWB + (((hci >> 3) ^ ((hrloc >> 1) & 3)) * 16) + (hci & 7) * 2;

    // ---------- prologue: W(0) DMA + x(0) stage ----------
    {
        gload_lds16(wimg + (wave * 2) * 1024 + lane * 16, wlds + (wave * 2) * 1024);
        gload_lds16(wimg + (wave * 2 + 1) * 1024 + lane * 16, wlds + (wave * 2 + 1) * 1024);
        float v[16];
#pragma unroll
        for (int j = 0; j < 16; ++j)
            v[j] = xcol[(size_t)(h * 16 + j) * NW];
        float hvv = xb[(size_t)hci * NW + hwc];
        u32 p[8];
#pragma unroll
        for (int jp = 0; jp < 8; ++jp)
            p[jp] = (u32)bf16bits(v[2 * jp]) | ((u32)bf16bits(v[2 * jp + 1]) << 16);
        *(int4*)(xlds + soff0) = *(int4*)&p[0];
        *(int4*)(xlds + soff1) = *(int4*)&p[4];
        if ((lane & 63) < 16)
            *(u16*)(xlds + hoff) = bf16bits(hok ? hvv : 0.f);
        LK0; VM0;
    }
    FENCE; __builtin_amdgcn_s_barrier(); FENCE;

    // ---------- main loop: 8 cb x 5 tap-steps ----------
    float v[16];
    float hvv = 0.f;
    for (int cb = 0; cb < 8; ++cb) {
        const char* xcur = xlds + (cb & 1) * XBUF;
        char* xnxt       = xlds + ((cb + 1) & 1) * XBUF;
        const bool more  = (cb < 7);
#pragma unroll
        for (int t = 0; t < NK; ++t) {
            const int s = cb * NK + t;
            // 1. issue next W-DMA (16 KB, L2-hot)
            if (s < 39) {
                const char* src = wimg + (size_t)(s + 1) * WSTEP;
                char* dst = wlds + ((s + 1) & 1) * WSTEP;
                gload_lds16(src + (wave * 2) * 1024 + lane * 16, dst + (wave * 2) * 1024);
                gload_lds16(src + (wave * 2 + 1) * 1024 + lane * 16, dst + (wave * 2 + 1) * 1024);
            }
            FENCE;
            // 2. issue x slice for cb+1 (4 HBM loads; halo at t=0)
            if (t < 4 && more) {
                const float* sx = xcol + (size_t)((cb + 1) * 32 + h * 16 + t * 4) * NW;
                v[t * 4 + 0] = sx[0];
                v[t * 4 + 1] = sx[(size_t)NW];
                v[t * 4 + 2] = sx[(size_t)2 * NW];
                v[t * 4 + 3] = sx[(size_t)3 * NW];
            }
            if (t == 0 && more)
                hvv = xb[(size_t)((cb + 1) * 32 + hci) * NW + hwc];
            FENCE;
            // 3. fragments (LDS only)
            const char* wcur = wlds + (s & 1) * WSTEP;
            short8 af[8], bf[4];
#pragma unroll
            for (int mi = 0; mi < 8; ++mi) {
                int rw = wm * 128 + mi * 16 + mrow;
                af[mi] = *(const short8*)(wcur + rw * 64 + ((g * 16) ^ XSWZ(rw)));
            }
#pragma unroll
            for (int ni = 0; ni < 4; ++ni) {
                int rx = wn * 64 + ni * 16 + mrow + t;
                bf[ni] = *(const short8*)(xcur + rx * XROWB + ((g * 16) ^ XSWZ(rx)));
            }
            // 4. MFMA cluster
            __builtin_amdgcn_s_setprio(1);
#pragma unroll
            for (int mi = 0; mi < 8; ++mi)
#pragma unroll
                for (int ni = 0; ni < 4; ++ni)
                    acc[mi][ni] = __builtin_amdgcn_mfma_f32_16x16x32_bf16(
                        af[mi], bf[ni], acc[mi][ni], 0, 0, 0);
            __builtin_amdgcn_s_setprio(0);
            // 5. write-late x for cb+1
            if (t == 4 && more) {
                u32 p[8];
#pragma unroll
                for (int jp = 0; jp < 8; ++jp)
                    p[jp] = (u32)bf16bits(v[2 * jp]) | ((u32)bf16bits(v[2 * jp + 1]) << 16);
                *(int4*)(xnxt + soff0) = *(int4*)&p[0];
                *(int4*)(xnxt + soff1) = *(int4*)&p[4];
                if ((lane & 63) < 16)
                    *(u16*)(xnxt + hoff) = bf16bits(hok ? hvv : 0.f);
            }
            // 6. step end: drain own VMEM/LDS, join
            LK0; VM0;
            FENCE; __builtin_amdgcn_s_barrier(); FENCE;
        }
    }

    // ---------- epilogue: C/D col=lane&15 (w), row=g*4+r (co) ----------
#pragma unroll
    for (int mi = 0; mi < 8; ++mi) {
        int cobase = wm * 128 + mi * 16 + g * 4;
        float bv[4];
#pragma unroll
        for (int r = 0; r < 4; ++r) bv[r] = bias[cobase + r];
#pragma unroll
        for (int ni = 0; ni < 4; ++ni) {
            int col = w0 + wn * 64 + ni * 16 + mrow;
#pragma unroll
            for (int r = 0; r < 4; ++r)
                out[((size_t)b * NCO + cobase + r) * NW + col] =
                    acc[mi][ni][r] + bv[r];
        }
    }
}

// ---------------- fallback (ws too small): naive fp32 ----------------

__global__ void conv_naive(const float* __restrict__ x, const float* __restrict__ wgt,
                           const float* __restrict__ bias, float* __restrict__ out) {
    int w  = blockIdx.x * 256 + threadIdx.x;
    int co = blockIdx.y;
    int b  = blockIdx.z;
    float acc = bias[co];
    for (int ci = 0; ci < NCI; ci++) {
        const float* xr = x + ((size_t)b * NCI + ci) * NW;
        const float* wr = wgt + ((size_t)co * NCI + ci) * NK;
#pragma unroll
        for (int k = 0; k < NK; k++) {
            int wi = w + k - 2;
            if (wi >= 0 && wi < NW) acc += xr[wi] * wr[k];
        }
    }
    out[((size_t)b * NCO + co) * NW + w] = acc;
}

// ---------------- launch ----------------

extern "C" void kernel_launch(void* const* d_in, const int* in_sizes, int n_in,
                              void* d_out, int out_size, void* d_ws, size_t ws_size,
                              hipStream_t stream) {
    const float* x    = (const float*)d_in[0];
    const float* wgt  = (const float*)d_in[1];
    const float* bias = (const float*)d_in[2];
    float* out        = (float*)d_out;

    if (ws_size < (size_t)W2_BYTES) {
        conv_naive<<<dim3(NW / 256, NCO, NB), 256, 0, stream>>>(x, wgt, bias, out);
        return;
    }

    u16* W2 = (u16*)d_ws;
    wprep<<<(NCO * NCI * NK + 255) / 256, 256, 0, stream>>>(wgt, W2);
    conv_mfma<<<512, 512, 0, stream>>>(x, W2, bias, out);
}